// Round 15
// baseline (132.985 us; speedup 1.0000x reference)
//
#include <hip/hip_runtime.h>
#include <math.h>

#define CC 10   // classes
#define KK 50   // neighbors

// ---- kA: 4 threads per row (contiguous 12/12/12/12+2 chunks) ---------------
// 262144 threads = 16 waves/CU (4x R14 concurrency); per-wave hot set 32KB
// fits L1 so intra-row line re-touches hit L1 instead of L2. Lean direct
// __expf accumulation (R14-validated); merge = 2-level shfl_xor of den+qh.
__global__ __launch_bounds__(256)
void kA(const float* __restrict__ aw, const float* __restrict__ an,
        const float* __restrict__ nbr, const float* __restrict__ att,
        const float* __restrict__ proj,
        float* __restrict__ wap, float* __restrict__ beta,
        int* __restrict__ flag0, int* __restrict__ hist, int B)
{
  int gt  = blockIdx.x * 256 + threadIdx.x;
  int row = gt >> 2;
  int j   = gt & 3;
  if (row >= B) return;

  // uniform coef (scalar loads): coef[c] = att[c] * proj[c][c]^2
  float coef[CC];
#pragma unroll
  for (int c = 0; c < CC; ++c) { float d = proj[c * CC + c]; coef[c] = att[c] * d * d; }

  // anchors row -> ci (4x redundant per row; L1 absorbs)
  const float2* anp = reinterpret_cast<const float2*>(an + (size_t)row * CC);
  float av[CC];
#pragma unroll
  for (int c2 = 0; c2 < CC / 2; ++c2) { float2 t = anp[c2]; av[2*c2] = t.x; av[2*c2+1] = t.y; }
  float ci[CC];
#pragma unroll
  for (int c = 0; c < CC; ++c) ci[c] = coef[c] * av[c];

  // this thread's contiguous neighbor chunk: k in [j*12, j*12+12), +tail 48+j (j<2)
  const float2* rowp = reinterpret_cast<const float2*>(nbr + (size_t)row * (KK * CC));
  float den = 0.f;
  float qh[CC];
#pragma unroll
  for (int c = 0; c < CC; ++c) qh[c] = 0.f;

  int ks = j * 12;
#pragma unroll 4
  for (int t = 0; t < 12; ++t) {
    int k = ks + t;
    float nb[CC];
#pragma unroll
    for (int c2 = 0; c2 < CC / 2; ++c2) {
      float2 v = rowp[k * (CC / 2) + c2];
      nb[2*c2] = v.x; nb[2*c2+1] = v.y;
    }
    float s = 0.f;
#pragma unroll
    for (int c = 0; c < CC; ++c) s = fmaf(ci[c], nb[c], s);
    s = (s > 0.f) ? s : 0.01f * s;          // leaky_relu
    float en[CC]; float sn = 0.f;
#pragma unroll
    for (int c = 0; c < CC; ++c) { en[c] = __expf(nb[c]); sn += en[c]; }
    float e = __expf(s);
    den += e;
    float esc = e * __builtin_amdgcn_rcpf(sn);
#pragma unroll
    for (int c = 0; c < CC; ++c) qh[c] = fmaf(esc, en[c], qh[c]);
  }
  if (j < 2) {                              // tail neighbors 48, 49
    int k = 48 + j;
    float nb[CC];
#pragma unroll
    for (int c2 = 0; c2 < CC / 2; ++c2) {
      float2 v = rowp[k * (CC / 2) + c2];
      nb[2*c2] = v.x; nb[2*c2+1] = v.y;
    }
    float s = 0.f;
#pragma unroll
    for (int c = 0; c < CC; ++c) s = fmaf(ci[c], nb[c], s);
    s = (s > 0.f) ? s : 0.01f * s;
    float en[CC]; float sn = 0.f;
#pragma unroll
    for (int c = 0; c < CC; ++c) { en[c] = __expf(nb[c]); sn += en[c]; }
    float e = __expf(s);
    den += e;
    float esc = e * __builtin_amdgcn_rcpf(sn);
#pragma unroll
    for (int c = 0; c < CC; ++c) qh[c] = fmaf(esc, en[c], qh[c]);
  }

  // merge the 4 partials (lanes differ in bits 0..1): plain sums
#pragma unroll
  for (int off = 1; off <= 2; off <<= 1) {
    den += __shfl_xor(den, off);
#pragma unroll
    for (int c = 0; c < CC; ++c) qh[c] += __shfl_xor(qh[c], off);
  }
  float invd = __builtin_amdgcn_rcpf(den);

  // beta = || softmax(an row) - qh/den ||^2  (all 4 lanes compute; j==0 stores)
  float ap[CC]; float s2 = 0.f;
#pragma unroll
  for (int c = 0; c < CC; ++c) { ap[c] = __expf(av[c]); s2 += ap[c]; }
  float inv2 = __builtin_amdgcn_rcpf(s2);
  float dd = 0.f;
#pragma unroll
  for (int c = 0; c < CC; ++c) { float d1 = ap[c] * inv2 - qh[c] * invd; dd = fmaf(d1, d1, dd); }

  // wap = softmax(aw row); flag0; hist
  const float2* awp = reinterpret_cast<const float2*>(aw + (size_t)row * CC);
  float wv[CC];
#pragma unroll
  for (int c2 = 0; c2 < CC / 2; ++c2) { float2 t = awp[c2]; wv[2*c2] = t.x; wv[2*c2+1] = t.y; }
  float ew[CC]; float sw = 0.f, mxw = 0.f;
#pragma unroll
  for (int c = 0; c < CC; ++c) { ew[c] = __expf(wv[c]); sw += ew[c]; mxw = fmaxf(mxw, ew[c]); }
  float rsw = __builtin_amdgcn_rcpf(sw);

  if (j == 0) {
    beta[row] = dd;
    float2* wq = reinterpret_cast<float2*>(wap + (size_t)row * CC);
#pragma unroll
    for (int c2 = 0; c2 < CC / 2; ++c2) {
      float2 t; t.x = ew[2*c2] * rsw; t.y = ew[2*c2+1] * rsw; wq[c2] = t;
    }
    int f = (mxw * rsw > 0.15f) ? 1 : 0;
    flag0[row] = f;
    if (f) atomicAdd(&hist[__float_as_uint(dd) >> 16], 1);  // beta>=0: order-preserving
  }
}

// ---------------- K3: exact radix select of k-th smallest beta --------------
// scal: [2]=sel_hi [3]=k2 [4]=k ; (float at [8]) = tau
__global__ __launch_bounds__(1024)
void k3b_sel(const int* __restrict__ hist, int* __restrict__ scal)
{
  __shared__ int tmp[1024];
  int t = threadIdx.x;
  int base = t * 64;
  const int4* h4 = reinterpret_cast<const int4*>(hist + base);
  int sum = 0;
#pragma unroll
  for (int jj = 0; jj < 16; ++jj) { int4 v = h4[jj]; sum += v.x + v.y + v.z + v.w; }
  tmp[t] = sum;
  __syncthreads();
  for (int off = 1; off < 1024; off <<= 1) {
    int v = (t >= off) ? tmp[t - off] : 0;
    __syncthreads();
    tmp[t] += v;
    __syncthreads();
  }
  int cumb = tmp[t] - sum;
  int b = tmp[1023];                 // total flagged count == b_count
  int k = (int)(0.5 * (double)b);    // int(ETA*b)
  if (k < 1) k = 1;
  if (t == 0) scal[4] = k;
  if (b > 0 && k > cumb && k <= cumb + sum) {
    int c = cumb;
    for (int jj = 0; jj < 64; ++jj) {
      int h = hist[base + jj];
      if (k <= c + h) { scal[2] = base + jj; scal[3] = k - c; break; }
      c += h;
    }
  }
  if (b == 0 && t == 0) { scal[2] = 0; scal[3] = 1; }
}

__global__ __launch_bounds__(256)
void k3c_hist2(const float* __restrict__ beta, const int* __restrict__ flag0,
               const int* __restrict__ scal, int* __restrict__ hist2, int B)
{
  int i = blockIdx.x * 256 + threadIdx.x;
  if (i >= B) return;
  if (flag0[i]) {
    unsigned key = __float_as_uint(beta[i]);
    if ((int)(key >> 16) == scal[2]) atomicAdd(&hist2[key & 0xFFFF], 1);
  }
}

__global__ __launch_bounds__(1024)
void k3d_tau(const int* __restrict__ hist2, int* __restrict__ scal,
             float* __restrict__ tau)
{
  __shared__ int tmp[1024];
  int t = threadIdx.x;
  int base = t * 64;
  const int4* h4 = reinterpret_cast<const int4*>(hist2 + base);
  int sum = 0;
#pragma unroll
  for (int jj = 0; jj < 16; ++jj) { int4 v = h4[jj]; sum += v.x + v.y + v.z + v.w; }
  tmp[t] = sum;
  __syncthreads();
  for (int off = 1; off < 1024; off <<= 1) {
    int v = (t >= off) ? tmp[t - off] : 0;
    __syncthreads();
    tmp[t] += v;
    __syncthreads();
  }
  int cumb = tmp[t] - sum;
  int k2 = scal[3];
  if (k2 > cumb && k2 <= cumb + sum) {
    int c = cumb;
    for (int jj = 0; jj < 64; ++jj) {
      int h = hist2[base + jj];
      if (k2 <= c + h) {
        unsigned key = (((unsigned)scal[2]) << 16) | (unsigned)(base + jj);
        float bk = __uint_as_float(key);
        *tau = bk / expf(-1.0f);
        break;
      }
      c += h;
    }
  }
}

// ---------------- K4: q, target, mask1, per-block counts --------------------
__global__ __launch_bounds__(256)
void k4_q(const float* __restrict__ wap, const float* __restrict__ beta,
          const int* __restrict__ flag0, const float* __restrict__ tau_p,
          float* __restrict__ qbuf, int* __restrict__ target, int* __restrict__ flag1,
          int* __restrict__ counts, int* __restrict__ blockcnt, int B)
{
  __shared__ int lcnt[CC];
  if (threadIdx.x < CC) lcnt[threadIdx.x] = 0;
  __syncthreads();

  int i = blockIdx.x * 256 + threadIdx.x;
  int f = 0;
  if (i < B) {
    float tau = *tau_p;
    float w[CC];
    const float2* p = reinterpret_cast<const float2*>(wap + (size_t)i * CC);
#pragma unroll
    for (int c = 0; c < CC / 2; ++c) { float2 t = p[c]; w[2*c] = t.x; w[2*c+1] = t.y; }
    float alpha = -__logf(beta[i] / tau);
    float q[CC];
    if (alpha > 1.0f) {
      float s = 0.f;
#pragma unroll
      for (int c = 0; c < CC; ++c) { q[c] = __expf(alpha * __logf(w[c])); s += q[c]; }
#pragma unroll
      for (int c = 0; c < CC; ++c) q[c] = q[c] / s;
    } else {
#pragma unroll
      for (int c = 0; c < CC; ++c) q[c] = w[c];
    }
    float mp = q[0]; int tg = 0;
#pragma unroll
    for (int c = 1; c < CC; ++c) if (q[c] > mp) { mp = q[c]; tg = c; }
    f = (flag0[i] && (mp > 0.1f)) ? 1 : 0;
    float2* qo = reinterpret_cast<float2*>(qbuf + (size_t)i * CC);
#pragma unroll
    for (int c = 0; c < CC / 2; ++c) { float2 t; t.x = q[2*c]; t.y = q[2*c+1]; qo[c] = t; }
    target[i] = tg;
    flag1[i] = f;
    if (f) atomicAdd(&lcnt[tg], 1);   // LDS atomic, contained in block
  }
  __shared__ int red[256];
  red[threadIdx.x] = f;
  __syncthreads();
  for (int off = 128; off; off >>= 1) {
    if (threadIdx.x < off) red[threadIdx.x] += red[threadIdx.x + off];
    __syncthreads();
  }
  if (threadIdx.x == 0) blockcnt[blockIdx.x] = red[0];
  if (threadIdx.x < CC) {
    int v = lcnt[threadIdx.x];
    if (v) atomicAdd(&counts[threadIdx.x], v);   // <=10 global atomics per block
  }
}

// ---------------- K6: self-scan block offsets, weights, outputs, loss parts -
__global__ __launch_bounds__(256)
void k6_out(const int* __restrict__ flag1, const int* __restrict__ target,
            const int* __restrict__ labels, const int* __restrict__ blockcnt,
            const float* __restrict__ a_strong, const float* __restrict__ qbuf,
            const int* __restrict__ counts, float* __restrict__ out,
            float* __restrict__ lossp, int n_host, int nb, int B)
{
  __shared__ int tmp[256];
  __shared__ float wavg_s[CC];
  int t = threadIdx.x;

  int bv = (t < nb) ? blockcnt[t] : 0;
  tmp[t] = bv;
  __syncthreads();
  for (int off = 1; off < 256; off <<= 1) {
    int u = (t >= off) ? tmp[t - off] : 0;
    __syncthreads();
    tmp[t] += u;
    __syncthreads();
  }
  int n    = tmp[255];
  int boff = (blockIdx.x > 0) ? tmp[blockIdx.x - 1] : 0;
  if (t == 0) {
    float wt[CC]; float sumw = 0.f;
    for (int c = 0; c < CC; ++c) {
      int cnt = counts[c];
      float w_ = (cnt > 0) ? 1.0f / logf(1.02f + (float)cnt / (float)n) : 1.0f;
      wt[c] = w_; sumw += w_;
    }
    float meanw = sumw / (float)CC;
    for (int c = 0; c < CC; ++c) wavg_s[c] = wt[c] / sumw * meanw;
  }
  __syncthreads();

  int i = blockIdx.x * 256 + t;
  int f = (i < B) ? flag1[i] : 0;
  tmp[t] = f;
  __syncthreads();
  for (int off = 1; off < 256; off <<= 1) {
    int u = (t >= off) ? tmp[t - off] : 0;
    __syncthreads();
    tmp[t] += u;
    __syncthreads();
  }
  int pos = boff + tmp[t] - f;
  float part = 0.f;
  if (f) {
    out[1 + pos] = (float)target[i];
    out[1 + n_host + pos] = (float)labels[i];
    float x[CC];
    const float2* p = reinterpret_cast<const float2*>(a_strong + (size_t)i * CC);
#pragma unroll
    for (int c = 0; c < CC / 2; ++c) { float2 u2 = p[c]; x[2*c] = u2.x; x[2*c+1] = u2.y; }
    float m = x[0];
#pragma unroll
    for (int c = 1; c < CC; ++c) m = fmaxf(m, x[c]);
    float s = 0.f;
#pragma unroll
    for (int c = 0; c < CC; ++c) s += __expf(x[c] - m);
    float lse = m + __logf(s);
    const float2* qp = reinterpret_cast<const float2*>(qbuf + (size_t)i * CC);
    float q[CC];
#pragma unroll
    for (int c = 0; c < CC / 2; ++c) { float2 u2 = qp[c]; q[2*c] = u2.x; q[2*c+1] = u2.y; }
#pragma unroll
    for (int c = 0; c < CC; ++c) part += wavg_s[c] * q[c] * (x[c] - lse);
  }
  __shared__ float red[256];
  red[t] = part;
  __syncthreads();
  for (int off = 128; off; off >>= 1) {
    if (t < off) red[t] += red[t + off];
    __syncthreads();
  }
  if (t == 0) lossp[blockIdx.x] = red[0];
}

// ---------------- K7: finalize ----------------------------------------------
__global__ __launch_bounds__(256)
void k7_fin(const float* __restrict__ lossp, int nb, const int* __restrict__ blockcnt,
            float* __restrict__ out, int n_host)
{
  __shared__ float red[256];
  __shared__ int   redi[256];
  int t = threadIdx.x;
  float s = 0.f; int ns = 0;
  for (int jj = t; jj < nb; jj += 256) { s += lossp[jj]; ns += blockcnt[jj]; }
  red[t] = s; redi[t] = ns;
  __syncthreads();
  for (int off = 128; off; off >>= 1) {
    if (t < off) { red[t] += red[t + off]; redi[t] += redi[t + off]; }
    __syncthreads();
  }
  if (t == 0) {
    int n = redi[0];
    out[0] = -red[0] / (float)n;
    out[1 + 2 * n_host] = (float)n;
  }
}

extern "C" void kernel_launch(void* const* d_in, const int* in_sizes, int n_in,
                              void* d_out, int out_size, void* d_ws, size_t ws_size,
                              hipStream_t stream)
{
  const float* aw     = (const float*)d_in[0];
  const float* astr   = (const float*)d_in[1];
  const float* an     = (const float*)d_in[2];
  const float* nbr    = (const float*)d_in[3];
  const int*   labels = (const int*)d_in[4];
  const float* att    = (const float*)d_in[6];
  const float* proj   = (const float*)d_in[7];
  float* out = (float*)d_out;

  int B = in_sizes[4];
  int C = in_sizes[6];
  int K = (B > 0 && C > 0) ? in_sizes[3] / (B * C) : 0;
  if (C != CC || K != KK) return;
  int n_host = (out_size - 2) / 2;
  int nb = (B + 255) / 256;
  if (nb > 256) return;

  char* w = (char*)d_ws;
  size_t o = 0;
  auto alloc = [&](size_t bytes) { size_t r = o; o += (bytes + 255) & ~(size_t)255; return r; };
  size_t o_wap  = alloc((size_t)B * CC * 4);
  size_t o_q    = alloc((size_t)B * CC * 4);
  size_t o_beta = alloc((size_t)B * 4);
  size_t o_tgt  = alloc((size_t)B * 4);
  size_t o_f0   = alloc((size_t)B * 4);
  size_t o_f1   = alloc((size_t)B * 4);
  size_t o_bc   = alloc((size_t)nb * 4);
  size_t o_lp   = alloc((size_t)nb * 4);
  size_t zstart = o;                       // zeroed-by-memset: h1, h2, cnt, scal
  size_t o_h1   = alloc(65536 * 4);
  size_t o_h2   = alloc(65536 * 4);
  size_t o_cnt  = alloc(64);
  size_t o_scal = alloc(64);
  size_t ztotal = o - zstart;
  if (o > ws_size) return;

  float* wap   = (float*)(w + o_wap);
  float* qbuf  = (float*)(w + o_q);
  float* beta  = (float*)(w + o_beta);
  int*   tgt   = (int*)(w + o_tgt);
  int*   f0    = (int*)(w + o_f0);
  int*   f1    = (int*)(w + o_f1);
  int*   bcnt  = (int*)(w + o_bc);
  float* lossp = (float*)(w + o_lp);
  int*   h1    = (int*)(w + o_h1);
  int*   h2    = (int*)(w + o_h2);
  int*   cnts  = (int*)(w + o_cnt);
  int*   scal  = (int*)(w + o_scal);
  float* taup  = (float*)(scal + 8);

  hipMemsetAsync(w + zstart, 0, ztotal, stream);

  int nbA = (B * 4 + 255) / 256;           // 4 threads per row
  kA      <<<nbA, 256, 0, stream>>>(aw, an, nbr, att, proj, wap, beta, f0, h1, B);
  k3b_sel <<<1, 1024, 0, stream>>>(h1, scal);
  k3c_hist2<<<nb, 256, 0, stream>>>(beta, f0, scal, h2, B);
  k3d_tau <<<1, 1024, 0, stream>>>(h2, scal, taup);
  k4_q    <<<nb, 256, 0, stream>>>(wap, beta, f0, taup, qbuf, tgt, f1,
                                   cnts, bcnt, B);
  k6_out  <<<nb, 256, 0, stream>>>(f1, tgt, labels, bcnt, astr, qbuf, cnts,
                                   out, lossp, n_host, nb, B);
  k7_fin  <<<1, 256, 0, stream>>>(lossp, nb, bcnt, out, n_host);
}

// Round 16
// 98.562 us; speedup vs baseline: 1.3492x; 1.3492x over previous
//
#include <hip/hip_runtime.h>
#include <math.h>

#define CC 10   // classes
#define KK 50   // neighbors

// ---- kA: THREAD-per-row (R14 structure), float4 pair-loads, deep unroll ----
// 1 wave/SIMD (grid-limited) -> latency exposure dominates; fix = fewer,
// wider, deeper-batched loads: 2 neighbors per 5xfloat4, unroll 5 pairs.
__global__ __launch_bounds__(256)
void kA(const float* __restrict__ aw, const float* __restrict__ an,
        const float* __restrict__ nbr, const float* __restrict__ att,
        const float* __restrict__ proj,
        float* __restrict__ wap, float* __restrict__ beta,
        int* __restrict__ flag0, int* __restrict__ hist, int B)
{
  int i = blockIdx.x * 256 + threadIdx.x;
  if (i >= B) return;

  // uniform coef (scalar loads): coef[c] = att[c] * proj[c][c]^2
  float coef[CC];
#pragma unroll
  for (int c = 0; c < CC; ++c) { float d = proj[c * CC + c]; coef[c] = att[c] * d * d; }

  // anchors row -> ci
  const float2* anp = reinterpret_cast<const float2*>(an + (size_t)i * CC);
  float av[CC];
#pragma unroll
  for (int c2 = 0; c2 < CC / 2; ++c2) { float2 t = anp[c2]; av[2*c2] = t.x; av[2*c2+1] = t.y; }
  float ci[CC];
#pragma unroll
  for (int c = 0; c < CC; ++c) ci[c] = coef[c] * av[c];

  float den = 0.f;
  float qh[CC];
#pragma unroll
  for (int c = 0; c < CC; ++c) qh[c] = 0.f;

  auto accum = [&](const float (&nb)[CC]) {
    float s = 0.f;
#pragma unroll
    for (int c = 0; c < CC; ++c) s = fmaf(ci[c], nb[c], s);
    s = (s > 0.f) ? s : 0.01f * s;          // leaky_relu
    float en[CC]; float sn = 0.f;
#pragma unroll
    for (int c = 0; c < CC; ++c) { en[c] = __expf(nb[c]); sn += en[c]; }
    float e = __expf(s);
    den += e;
    float esc = e * __builtin_amdgcn_rcpf(sn);
#pragma unroll
    for (int c = 0; c < CC; ++c) qh[c] = fmaf(esc, en[c], qh[c]);
  };

  // stream neighbors as 25 pairs: 5 x float4 per pair (row is 16B-aligned)
  const float4* rowp4 = reinterpret_cast<const float4*>(nbr + (size_t)i * (KK * CC));
#pragma unroll 5
  for (int p = 0; p < 25; ++p) {
    float4 va = rowp4[p * 5 + 0];
    float4 vb = rowp4[p * 5 + 1];
    float4 vc = rowp4[p * 5 + 2];
    float4 vd = rowp4[p * 5 + 3];
    float4 ve = rowp4[p * 5 + 4];
    float nbA[CC] = {va.x, va.y, va.z, va.w, vb.x, vb.y, vb.z, vb.w, vc.x, vc.y};
    float nbB[CC] = {vc.z, vc.w, vd.x, vd.y, vd.z, vd.w, ve.x, ve.y, ve.z, ve.w};
    accum(nbA);
    accum(nbB);
  }
  float invd = __builtin_amdgcn_rcpf(den);

  // beta = || softmax(an row) - qh/den ||^2
  float ap[CC]; float s2 = 0.f;
#pragma unroll
  for (int c = 0; c < CC; ++c) { ap[c] = __expf(av[c]); s2 += ap[c]; }
  float inv2 = __builtin_amdgcn_rcpf(s2);
  float dd = 0.f;
#pragma unroll
  for (int c = 0; c < CC; ++c) { float d1 = ap[c] * inv2 - qh[c] * invd; dd = fmaf(d1, d1, dd); }
  beta[i] = dd;

  // wap = softmax(aw row); flag0; hist
  const float2* awp = reinterpret_cast<const float2*>(aw + (size_t)i * CC);
  float wv[CC];
#pragma unroll
  for (int c2 = 0; c2 < CC / 2; ++c2) { float2 t = awp[c2]; wv[2*c2] = t.x; wv[2*c2+1] = t.y; }
  float ew[CC]; float sw = 0.f, mxw = 0.f;
#pragma unroll
  for (int c = 0; c < CC; ++c) { ew[c] = __expf(wv[c]); sw += ew[c]; mxw = fmaxf(mxw, ew[c]); }
  float rsw = __builtin_amdgcn_rcpf(sw);
  float2* wq = reinterpret_cast<float2*>(wap + (size_t)i * CC);
#pragma unroll
  for (int c2 = 0; c2 < CC / 2; ++c2) {
    float2 t; t.x = ew[2*c2] * rsw; t.y = ew[2*c2+1] * rsw; wq[c2] = t;
  }
  int f = (mxw * rsw > 0.15f) ? 1 : 0;
  flag0[i] = f;
  if (f) atomicAdd(&hist[__float_as_uint(dd) >> 16], 1);  // beta>=0: order-preserving
}

// ---------------- K3: exact radix select of k-th smallest beta --------------
// scal: [2]=sel_hi [3]=k2 [4]=k ; (float at [8]) = tau
__global__ __launch_bounds__(1024)
void k3b_sel(const int* __restrict__ hist, int* __restrict__ scal)
{
  __shared__ int tmp[1024];
  int t = threadIdx.x;
  int base = t * 64;
  const int4* h4 = reinterpret_cast<const int4*>(hist + base);
  int sum = 0;
#pragma unroll
  for (int jj = 0; jj < 16; ++jj) { int4 v = h4[jj]; sum += v.x + v.y + v.z + v.w; }
  tmp[t] = sum;
  __syncthreads();
  for (int off = 1; off < 1024; off <<= 1) {
    int v = (t >= off) ? tmp[t - off] : 0;
    __syncthreads();
    tmp[t] += v;
    __syncthreads();
  }
  int cumb = tmp[t] - sum;
  int b = tmp[1023];                 // total flagged count == b_count
  int k = (int)(0.5 * (double)b);    // int(ETA*b)
  if (k < 1) k = 1;
  if (t == 0) scal[4] = k;
  if (b > 0 && k > cumb && k <= cumb + sum) {
    int c = cumb;
    for (int jj = 0; jj < 64; ++jj) {
      int h = hist[base + jj];
      if (k <= c + h) { scal[2] = base + jj; scal[3] = k - c; break; }
      c += h;
    }
  }
  if (b == 0 && t == 0) { scal[2] = 0; scal[3] = 1; }
}

__global__ __launch_bounds__(256)
void k3c_hist2(const float* __restrict__ beta, const int* __restrict__ flag0,
               const int* __restrict__ scal, int* __restrict__ hist2, int B)
{
  int i = blockIdx.x * 256 + threadIdx.x;
  if (i >= B) return;
  if (flag0[i]) {
    unsigned key = __float_as_uint(beta[i]);
    if ((int)(key >> 16) == scal[2]) atomicAdd(&hist2[key & 0xFFFF], 1);
  }
}

__global__ __launch_bounds__(1024)
void k3d_tau(const int* __restrict__ hist2, int* __restrict__ scal,
             float* __restrict__ tau)
{
  __shared__ int tmp[1024];
  int t = threadIdx.x;
  int base = t * 64;
  const int4* h4 = reinterpret_cast<const int4*>(hist2 + base);
  int sum = 0;
#pragma unroll
  for (int jj = 0; jj < 16; ++jj) { int4 v = h4[jj]; sum += v.x + v.y + v.z + v.w; }
  tmp[t] = sum;
  __syncthreads();
  for (int off = 1; off < 1024; off <<= 1) {
    int v = (t >= off) ? tmp[t - off] : 0;
    __syncthreads();
    tmp[t] += v;
    __syncthreads();
  }
  int cumb = tmp[t] - sum;
  int k2 = scal[3];
  if (k2 > cumb && k2 <= cumb + sum) {
    int c = cumb;
    for (int jj = 0; jj < 64; ++jj) {
      int h = hist2[base + jj];
      if (k2 <= c + h) {
        unsigned key = (((unsigned)scal[2]) << 16) | (unsigned)(base + jj);
        float bk = __uint_as_float(key);
        *tau = bk / expf(-1.0f);
        break;
      }
      c += h;
    }
  }
}

// ---------------- K4: q, target, mask1, per-block counts --------------------
__global__ __launch_bounds__(256)
void k4_q(const float* __restrict__ wap, const float* __restrict__ beta,
          const int* __restrict__ flag0, const float* __restrict__ tau_p,
          float* __restrict__ qbuf, int* __restrict__ target, int* __restrict__ flag1,
          int* __restrict__ counts, int* __restrict__ blockcnt, int B)
{
  __shared__ int lcnt[CC];
  if (threadIdx.x < CC) lcnt[threadIdx.x] = 0;
  __syncthreads();

  int i = blockIdx.x * 256 + threadIdx.x;
  int f = 0;
  if (i < B) {
    float tau = *tau_p;
    float w[CC];
    const float2* p = reinterpret_cast<const float2*>(wap + (size_t)i * CC);
#pragma unroll
    for (int c = 0; c < CC / 2; ++c) { float2 t = p[c]; w[2*c] = t.x; w[2*c+1] = t.y; }
    float alpha = -__logf(beta[i] / tau);
    float q[CC];
    if (alpha > 1.0f) {
      float s = 0.f;
#pragma unroll
      for (int c = 0; c < CC; ++c) { q[c] = __expf(alpha * __logf(w[c])); s += q[c]; }
#pragma unroll
      for (int c = 0; c < CC; ++c) q[c] = q[c] / s;
    } else {
#pragma unroll
      for (int c = 0; c < CC; ++c) q[c] = w[c];
    }
    float mp = q[0]; int tg = 0;
#pragma unroll
    for (int c = 1; c < CC; ++c) if (q[c] > mp) { mp = q[c]; tg = c; }
    f = (flag0[i] && (mp > 0.1f)) ? 1 : 0;
    float2* qo = reinterpret_cast<float2*>(qbuf + (size_t)i * CC);
#pragma unroll
    for (int c = 0; c < CC / 2; ++c) { float2 t; t.x = q[2*c]; t.y = q[2*c+1]; qo[c] = t; }
    target[i] = tg;
    flag1[i] = f;
    if (f) atomicAdd(&lcnt[tg], 1);   // LDS atomic, contained in block
  }
  __shared__ int red[256];
  red[threadIdx.x] = f;
  __syncthreads();
  for (int off = 128; off; off >>= 1) {
    if (threadIdx.x < off) red[threadIdx.x] += red[threadIdx.x + off];
    __syncthreads();
  }
  if (threadIdx.x == 0) blockcnt[blockIdx.x] = red[0];
  if (threadIdx.x < CC) {
    int v = lcnt[threadIdx.x];
    if (v) atomicAdd(&counts[threadIdx.x], v);   // <=10 global atomics per block
  }
}

// ---------------- K6: self-scan block offsets, weights, outputs, loss parts -
__global__ __launch_bounds__(256)
void k6_out(const int* __restrict__ flag1, const int* __restrict__ target,
            const int* __restrict__ labels, const int* __restrict__ blockcnt,
            const float* __restrict__ a_strong, const float* __restrict__ qbuf,
            const int* __restrict__ counts, float* __restrict__ out,
            float* __restrict__ lossp, int n_host, int nb, int B)
{
  __shared__ int tmp[256];
  __shared__ float wavg_s[CC];
  int t = threadIdx.x;

  int bv = (t < nb) ? blockcnt[t] : 0;
  tmp[t] = bv;
  __syncthreads();
  for (int off = 1; off < 256; off <<= 1) {
    int u = (t >= off) ? tmp[t - off] : 0;
    __syncthreads();
    tmp[t] += u;
    __syncthreads();
  }
  int n    = tmp[255];
  int boff = (blockIdx.x > 0) ? tmp[blockIdx.x - 1] : 0;
  if (t == 0) {
    float wt[CC]; float sumw = 0.f;
    for (int c = 0; c < CC; ++c) {
      int cnt = counts[c];
      float w_ = (cnt > 0) ? 1.0f / logf(1.02f + (float)cnt / (float)n) : 1.0f;
      wt[c] = w_; sumw += w_;
    }
    float meanw = sumw / (float)CC;
    for (int c = 0; c < CC; ++c) wavg_s[c] = wt[c] / sumw * meanw;
  }
  __syncthreads();

  int i = blockIdx.x * 256 + t;
  int f = (i < B) ? flag1[i] : 0;
  tmp[t] = f;
  __syncthreads();
  for (int off = 1; off < 256; off <<= 1) {
    int u = (t >= off) ? tmp[t - off] : 0;
    __syncthreads();
    tmp[t] += u;
    __syncthreads();
  }
  int pos = boff + tmp[t] - f;
  float part = 0.f;
  if (f) {
    out[1 + pos] = (float)target[i];
    out[1 + n_host + pos] = (float)labels[i];
    float x[CC];
    const float2* p = reinterpret_cast<const float2*>(a_strong + (size_t)i * CC);
#pragma unroll
    for (int c = 0; c < CC / 2; ++c) { float2 u2 = p[c]; x[2*c] = u2.x; x[2*c+1] = u2.y; }
    float m = x[0];
#pragma unroll
    for (int c = 1; c < CC; ++c) m = fmaxf(m, x[c]);
    float s = 0.f;
#pragma unroll
    for (int c = 0; c < CC; ++c) s += __expf(x[c] - m);
    float lse = m + __logf(s);
    const float2* qp = reinterpret_cast<const float2*>(qbuf + (size_t)i * CC);
    float q[CC];
#pragma unroll
    for (int c = 0; c < CC / 2; ++c) { float2 u2 = qp[c]; q[2*c] = u2.x; q[2*c+1] = u2.y; }
#pragma unroll
    for (int c = 0; c < CC; ++c) part += wavg_s[c] * q[c] * (x[c] - lse);
  }
  __shared__ float red[256];
  red[t] = part;
  __syncthreads();
  for (int off = 128; off; off >>= 1) {
    if (t < off) red[t] += red[t + off];
    __syncthreads();
  }
  if (t == 0) lossp[blockIdx.x] = red[0];
}

// ---------------- K7: finalize ----------------------------------------------
__global__ __launch_bounds__(256)
void k7_fin(const float* __restrict__ lossp, int nb, const int* __restrict__ blockcnt,
            float* __restrict__ out, int n_host)
{
  __shared__ float red[256];
  __shared__ int   redi[256];
  int t = threadIdx.x;
  float s = 0.f; int ns = 0;
  for (int jj = t; jj < nb; jj += 256) { s += lossp[jj]; ns += blockcnt[jj]; }
  red[t] = s; redi[t] = ns;
  __syncthreads();
  for (int off = 128; off; off >>= 1) {
    if (t < off) { red[t] += red[t + off]; redi[t] += redi[t + off]; }
    __syncthreads();
  }
  if (t == 0) {
    int n = redi[0];
    out[0] = -red[0] / (float)n;
    out[1 + 2 * n_host] = (float)n;
  }
}

extern "C" void kernel_launch(void* const* d_in, const int* in_sizes, int n_in,
                              void* d_out, int out_size, void* d_ws, size_t ws_size,
                              hipStream_t stream)
{
  const float* aw     = (const float*)d_in[0];
  const float* astr   = (const float*)d_in[1];
  const float* an     = (const float*)d_in[2];
  const float* nbr    = (const float*)d_in[3];
  const int*   labels = (const int*)d_in[4];
  const float* att    = (const float*)d_in[6];
  const float* proj   = (const float*)d_in[7];
  float* out = (float*)d_out;

  int B = in_sizes[4];
  int C = in_sizes[6];
  int K = (B > 0 && C > 0) ? in_sizes[3] / (B * C) : 0;
  if (C != CC || K != KK) return;
  int n_host = (out_size - 2) / 2;
  int nb = (B + 255) / 256;
  if (nb > 256) return;

  char* w = (char*)d_ws;
  size_t o = 0;
  auto alloc = [&](size_t bytes) { size_t r = o; o += (bytes + 255) & ~(size_t)255; return r; };
  size_t o_wap  = alloc((size_t)B * CC * 4);
  size_t o_q    = alloc((size_t)B * CC * 4);
  size_t o_beta = alloc((size_t)B * 4);
  size_t o_tgt  = alloc((size_t)B * 4);
  size_t o_f0   = alloc((size_t)B * 4);
  size_t o_f1   = alloc((size_t)B * 4);
  size_t o_bc   = alloc((size_t)nb * 4);
  size_t o_lp   = alloc((size_t)nb * 4);
  size_t zstart = o;                       // zeroed-by-memset: h1, h2, cnt, scal
  size_t o_h1   = alloc(65536 * 4);
  size_t o_h2   = alloc(65536 * 4);
  size_t o_cnt  = alloc(64);
  size_t o_scal = alloc(64);
  size_t ztotal = o - zstart;
  if (o > ws_size) return;

  float* wap   = (float*)(w + o_wap);
  float* qbuf  = (float*)(w + o_q);
  float* beta  = (float*)(w + o_beta);
  int*   tgt   = (int*)(w + o_tgt);
  int*   f0    = (int*)(w + o_f0);
  int*   f1    = (int*)(w + o_f1);
  int*   bcnt  = (int*)(w + o_bc);
  float* lossp = (float*)(w + o_lp);
  int*   h1    = (int*)(w + o_h1);
  int*   h2    = (int*)(w + o_h2);
  int*   cnts  = (int*)(w + o_cnt);
  int*   scal  = (int*)(w + o_scal);
  float* taup  = (float*)(scal + 8);

  hipMemsetAsync(w + zstart, 0, ztotal, stream);

  kA      <<<nb, 256, 0, stream>>>(aw, an, nbr, att, proj, wap, beta, f0, h1, B);
  k3b_sel <<<1, 1024, 0, stream>>>(h1, scal);
  k3c_hist2<<<nb, 256, 0, stream>>>(beta, f0, scal, h2, B);
  k3d_tau <<<1, 1024, 0, stream>>>(h2, scal, taup);
  k4_q    <<<nb, 256, 0, stream>>>(wap, beta, f0, taup, qbuf, tgt, f1,
                                   cnts, bcnt, B);
  k6_out  <<<nb, 256, 0, stream>>>(f1, tgt, labels, bcnt, astr, qbuf, cnts,
                                   out, lossp, n_host, nb, B);
  k7_fin  <<<1, 256, 0, stream>>>(lossp, nb, bcnt, out, n_host);
}